// Round 13
// baseline (610.124 us; speedup 1.0000x reference)
//
#include <hip/hip_runtime.h>
#include <hip/hip_fp16.h>
#include <math.h>

namespace {

typedef __attribute__((ext_vector_type(8))) short short8;
typedef __attribute__((ext_vector_type(4))) float f32x4;

constexpr float kPI = 3.14159265358979323846f;

__device__ __forceinline__ unsigned short f2bf(float f) {
    unsigned int u = __float_as_uint(f);
    u += 0x7fffu + ((u >> 16) & 1u);
    return (unsigned short)(u >> 16);
}

__device__ __forceinline__ short8 pack8(const float* f) {
    short8 r;
    #pragma unroll
    for (int i = 0; i < 8; ++i) r[i] = (short)f2bf(f[i]);
    return r;
}

__device__ __forceinline__ f32x4 MFMA(short8 a, short8 b, f32x4 c) {
    return __builtin_amdgcn_mfma_f32_16x16x32_bf16(a, b, c, 0, 0, 0);
}

// ---- weight pre-arrangement into B-fragment order (bf16) ----
// chunk = (adv, kstep, ntile): 64 lanes x 8 bf16; lane l holds
// B[k = kstep*32 + (l>>4)*8 + i][col = ntile*16 + (l&15)].
__global__ __launch_bounds__(256)
void prep_weights(const float* __restrict__ Wq, const float* __restrict__ Wk,
                  const float* __restrict__ Wv, const float* __restrict__ Wo,
                  short* __restrict__ wsQ, short* __restrict__ wsKV,
                  short* __restrict__ wsO)
{
    const int cid = blockIdx.x * 4 + (threadIdx.x >> 6);
    const int l = threadIdx.x & 63;
    const int lr = l & 15, lk = l >> 4;
    const int arr = cid >> 10, c2 = cid & 1023;
    const int adv = c2 >> 7, ks = (c2 >> 4) & 7, nt = c2 & 15;
    const int c0 = ks * 32 + lk * 8;
    float v[8];
    if (arr == 0) {                       // Wq[c][adv][j], j in [0,256)
        const int j = nt * 16 + lr;
        #pragma unroll
        for (int i = 0; i < 8; ++i)
            v[i] = Wq[((size_t)(c0 + i) * 8 + adv) * 256 + j];
    } else if (arr == 1) {                // K (nt<8) then V (nt>=8), j in [0,128)
        if (nt < 8) {
            const int j = nt * 16 + lr;
            #pragma unroll
            for (int i = 0; i < 8; ++i)
                v[i] = Wk[((size_t)(c0 + i) * 8 + adv) * 128 + j];
        } else {
            const int j = (nt - 8) * 16 + lr;
            #pragma unroll
            for (int i = 0; i < 8; ++i)
                v[i] = Wv[((size_t)(c0 + i) * 8 + adv) * 128 + j];
        }
    } else {                              // Wo[adv][j][c]: k=j, col=c
        const int cc = nt * 16 + lr;
        #pragma unroll
        for (int i = 0; i < 8; ++i)
            v[i] = Wo[((size_t)adv * 256 + (c0 + i)) * 256 + cc];
    }
    short* dst = (arr == 0 ? wsQ : arr == 1 ? wsKV : wsO) + (size_t)c2 * 512 + l * 8;
    *(short8*)dst = pack8(v);
}

// ---- fused per-line axial attention; all GEMMs + attention on MFMA ----
// block = (b, line); 512 threads = 8 waves. TWO (d,v) slices per phase-pass:
// shared xs A-frags, shared csl2 reads, shared oacc; 8 independent MFMAs per
// k-step; 5 barriers/kernel. LDS = 144 KB -> 1 block/CU (deliberate: the
// (512,4) 128-reg budget spilled 60-150 MB/dispatch in rounds 8-12; here the
// 256-reg budget of __launch_bounds__(512,2) fits the ~200-reg natural demand
// with zero spills, and pair-ILP + fewer barriers supply the latency hiding).
template <int AXIS, bool ACCUM>
__global__ __launch_bounds__(512, 2)
void axial_attn_mfma(const float* __restrict__ x,
                     const float* __restrict__ xpos,
                     const float* __restrict__ ypos,
                     const float* __restrict__ bvp,
                     const float* __restrict__ rfreq,
                     const short* __restrict__ wsQ,
                     const short* __restrict__ wsKV,
                     const short* __restrict__ wsO,
                     float* __restrict__ out)
{
    __shared__ __align__(16) short xs[32 * 256];     // x line bf16, elem ^ ((row&7)<<3)
    __shared__ __align__(16) short qbufA[32 * 256];  // Qr bf16, swizzled
    __shared__ __align__(16) short qbufB[32 * 256];
    __shared__ __align__(16) short kbufA[32 * 256];  // Kr bf16 (with m)
    __shared__ __align__(16) short kbufB[32 * 256];
    __shared__ __align__(16) short vbufA[4 * 32 * 32]; // V^T [kk][dv][s ^ ((dv&3)<<3)]
    __shared__ __align__(16) short vbufB[4 * 32 * 32];
    __shared__ __align__(16) short obufA[32 * 256];  // attn out bf16
    __shared__ __align__(16) short obufB[32 * 256];
    __shared__ __half2 csl2[32 * 128];               // [pos][r ^ (pos&15)] = (cos,sin)

    const int t = threadIdx.x;
    const int b = blockIdx.x >> 5;
    const int line = blockIdx.x & 31;
    const int w = t >> 6, l = t & 63;
    const int lr = l & 15, lk = l >> 4;
    const int p01 = l & 1;

    // ---- stage x line into xs (bf16, swizzled): 16 elems/thread ----
    {
        const int row = t >> 4;
        const int c0 = (t & 15) * 16;
        const int gy = (AXIS == 0) ? row : line;
        const int gx = (AXIS == 0) ? line : row;
        const float* px = x + ((size_t)((b * 32 + gy) * 32 + gx)) * 256 + c0;
        float tmp[16];
        #pragma unroll
        for (int i = 0; i < 16; i += 4) {
            const float4 a = *(const float4*)(px + i);
            tmp[i] = a.x; tmp[i + 1] = a.y; tmp[i + 2] = a.z; tmp[i + 3] = a.w;
        }
        const int swz = (row & 7) << 3;
        *(short8*)&xs[row * 256 + (c0 ^ swz)] = pack8(tmp);
        *(short8*)&xs[row * 256 + ((c0 + 8) ^ swz)] = pack8(tmp + 8);
    }
    // ---- RoPE cos/sin table (prologue-only trig) ----
    const float* posv = (AXIS == 0) ? ypos : xpos;
    for (int idx = t; idx < 32 * 128; idx += 512) {
        const int pos = idx >> 7, r = idx & 127;
        const int h = r & 15;
        const float s0 = kPI / (1.0f + (29.0f / 15.0f) * (float)h);
        const float s1 = kPI / (0.1f + 0.06f * (float)h);
        const float phi = rfreq[r * 2 + 0] * s0 * posv[pos * 2 + 0] +
                          rfreq[r * 2 + 1] * s1 * posv[pos * 2 + 1];
        float sv, cv;
        __sincosf(phi, &sv, &cv);
        csl2[pos * 128 + (r ^ (pos & 15))] = __floats2half2_rn(cv, sv);
    }
    __syncthreads();

    f32x4 oacc[2][2] = {};
    const short8* wsQv  = (const short8*)wsQ;
    const short8* wsKVv = (const short8*)wsKV;
    const short8* wsOv  = (const short8*)wsO;
    const int m_w = w >> 2, kk_w = w & 3;
    const int aswz = (lr & 7) << 3;   // row&7 == lr&7 for rows lr and 16+lr

    for (int pr = 0; pr < 2; ++pr) {
        const int advA = AXIS * 4 + pr * 2;
        const int advB = advA + 1;
        const float sgn = (pr == 0) ? 1.0f : -1.0f;   // d = pr (slices 2pr, 2pr+1)

        // ---------- Q projection (both slices) + RoPE -> qbufA/B ----------
        {
            f32x4 qA[2][2] = {}, qB[2][2] = {};
            #pragma unroll 2
            for (int ks = 0; ks < 8; ++ks) {
                const int e = (ks * 32 + lk * 8) ^ aswz;
                const short8 a0 = *(const short8*)&xs[lr * 256 + e];
                const short8 a1 = *(const short8*)&xs[(16 + lr) * 256 + e];
                const short8 bA0 = wsQv[(size_t)((advA * 8 + ks) * 16 + w * 2 + 0) * 64 + l];
                const short8 bA1 = wsQv[(size_t)((advA * 8 + ks) * 16 + w * 2 + 1) * 64 + l];
                const short8 bB0 = wsQv[(size_t)((advB * 8 + ks) * 16 + w * 2 + 0) * 64 + l];
                const short8 bB1 = wsQv[(size_t)((advB * 8 + ks) * 16 + w * 2 + 1) * 64 + l];
                qA[0][0] = MFMA(a0, bA0, qA[0][0]);
                qA[1][0] = MFMA(a1, bA0, qA[1][0]);
                qA[0][1] = MFMA(a0, bA1, qA[0][1]);
                qA[1][1] = MFMA(a1, bA1, qA[1][1]);
                qB[0][0] = MFMA(a0, bB0, qB[0][0]);
                qB[1][0] = MFMA(a1, bB0, qB[1][0]);
                qB[0][1] = MFMA(a0, bB1, qB[0][1]);
                qB[1][1] = MFMA(a1, bB1, qB[1][1]);
            }
            #pragma unroll
            for (int mt = 0; mt < 2; ++mt)
                #pragma unroll
                for (int nt = 0; nt < 2; ++nt) {
                    const int h = (nt * 16 + lr) >> 1;
                    const int csb = m_w * 64 + kk_w * 16 + h;
                    const int col = w * 32 + nt * 16 + lr;
                    #pragma unroll
                    for (int r = 0; r < 4; ++r) {
                        const int pos = mt * 16 + lk * 4 + r;
                        const __half2 csh = csl2[pos * 128 + (csb ^ (pos & 15))];
                        const float cv = __low2float(csh), sv = __high2float(csh);
                        const int off = pos * 256 + (col ^ ((pos & 7) << 3));
                        const float ownA = qA[mt][nt][r];
                        const float othA = __shfl_xor(ownA, 1);
                        qbufA[off] = (short)f2bf((p01 == 0) ? cv * ownA + sgn * sv * othA
                                                            : cv * ownA - sgn * sv * othA);
                        const float ownB = qB[mt][nt][r];
                        const float othB = __shfl_xor(ownB, 1);
                        qbufB[off] = (short)f2bf((p01 == 0) ? cv * ownB + sgn * sv * othB
                                                            : cv * ownB - sgn * sv * othB);
                    }
                }
        }

        // ---------- K/V projection (both slices) ----------
        {
            f32x4 kA[2][2] = {}, kB[2][2] = {};
            #pragma unroll 2
            for (int ks = 0; ks < 8; ++ks) {
                const int e = (ks * 32 + lk * 8) ^ aswz;
                const short8 a0 = *(const short8*)&xs[lr * 256 + e];
                const short8 a1 = *(const short8*)&xs[(16 + lr) * 256 + e];
                const short8 bA0 = wsKVv[(size_t)((advA * 8 + ks) * 16 + w * 2 + 0) * 64 + l];
                const short8 bA1 = wsKVv[(size_t)((advA * 8 + ks) * 16 + w * 2 + 1) * 64 + l];
                const short8 bB0 = wsKVv[(size_t)((advB * 8 + ks) * 16 + w * 2 + 0) * 64 + l];
                const short8 bB1 = wsKVv[(size_t)((advB * 8 + ks) * 16 + w * 2 + 1) * 64 + l];
                kA[0][0] = MFMA(a0, bA0, kA[0][0]);
                kA[1][0] = MFMA(a1, bA0, kA[1][0]);
                kA[0][1] = MFMA(a0, bA1, kA[0][1]);
                kA[1][1] = MFMA(a1, bA1, kA[1][1]);
                kB[0][0] = MFMA(a0, bB0, kB[0][0]);
                kB[1][0] = MFMA(a1, bB0, kB[1][0]);
                kB[0][1] = MFMA(a0, bB1, kB[0][1]);
                kB[1][1] = MFMA(a1, bB1, kB[1][1]);
            }
            if (w < 4) {
                #pragma unroll
                for (int mt = 0; mt < 2; ++mt)
                    #pragma unroll
                    for (int nt = 0; nt < 2; ++nt) {
                        const int h = (nt * 16 + lr) >> 1;
                        const int jl = nt * 16 + lr;
                        #pragma unroll
                        for (int r = 0; r < 4; ++r) {
                            const int pos = mt * 16 + lk * 4 + r;
                            const float ownA = kA[mt][nt][r];
                            const float othA = __shfl_xor(ownA, 1);
                            const float ownB = kB[mt][nt][r];
                            const float othB = __shfl_xor(ownB, 1);
                            #pragma unroll
                            for (int m2 = 0; m2 < 2; ++m2) {
                                const __half2 csh = csl2[pos * 128 + ((m2 * 64 + w * 16 + h) ^ (pos & 15))];
                                const float cv = __low2float(csh), sv = __high2float(csh);
                                const int off = pos * 256 +
                                    (((m2 * 4 + w) * 32 + jl) ^ ((pos & 7) << 3));
                                kbufA[off] = (short)f2bf((p01 == 0) ? cv * ownA + sgn * sv * othA
                                                                    : cv * ownA - sgn * sv * othA);
                                kbufB[off] = (short)f2bf((p01 == 0) ? cv * ownB + sgn * sv * othB
                                                                    : cv * ownB - sgn * sv * othB);
                            }
                        }
                    }
            } else {
                const int kk = w - 4;
                #pragma unroll
                for (int nt = 0; nt < 2; ++nt) {
                    const int dv = nt * 16 + lr;
                    const float bvvA = bvp[advA * 128 + kk * 32 + dv];
                    const float bvvB = bvp[advB * 128 + kk * 32 + dv];
                    #pragma unroll
                    for (int mt = 0; mt < 2; ++mt)
                        #pragma unroll
                        for (int r = 0; r < 4; ++r) {
                            const int s = mt * 16 + lk * 4 + r;
                            const int off = kk * 1024 + dv * 32 + (s ^ ((dv & 3) << 3));
                            vbufA[off] = (short)f2bf(kA[mt][nt][r] + bvvA);
                            vbufB[off] = (short)f2bf(kB[mt][nt][r] + bvvB);
                        }
                }
            }
        }
        __syncthreads();   // barrier 1: q/k/v (both slices) visible

        // ---------- attention (both slices): wave g; scores^T = mfma(Kr, Qr) ----------
        {
            const int g = w;
            short8 kaA[2], qaA[2], kaB[2], qaB[2];
            #pragma unroll
            for (int st = 0; st < 2; ++st) {
                const int row = st * 16 + lr;
                const int off = row * 256 + ((g * 32 + lk * 8) ^ ((row & 7) << 3));
                kaA[st] = *(const short8*)&kbufA[off];
                kaB[st] = *(const short8*)&kbufB[off];
                qaA[st] = *(const short8*)&qbufA[off];
                qaB[st] = *(const short8*)&qbufB[off];
            }
            f32x4 dA[2][2] = {}, dB[2][2] = {};
            #pragma unroll
            for (int st = 0; st < 2; ++st)
                #pragma unroll
                for (int qt = 0; qt < 2; ++qt) {
                    dA[st][qt] = MFMA(kaA[st], qaA[qt], dA[st][qt]);
                    dB[st][qt] = MFMA(kaB[st], qaB[qt], dB[st][qt]);
                }

            // sigmoid + pack pairs (consecutive s) to bf16 — plain bit ops
            unsigned int pkA[2][2][2], pkB[2][2][2];
            #pragma unroll
            for (int st = 0; st < 2; ++st)
                #pragma unroll
                for (int qt = 0; qt < 2; ++qt)
                    #pragma unroll
                    for (int h2 = 0; h2 < 2; ++h2) {
                        const float zaA = __builtin_amdgcn_rcpf(1.0f + __expf(-dA[st][qt][2 * h2]));
                        const float zbA = __builtin_amdgcn_rcpf(1.0f + __expf(-dA[st][qt][2 * h2 + 1]));
                        pkA[st][qt][h2] = (unsigned int)f2bf(zaA) |
                                          ((unsigned int)f2bf(zbA) << 16);
                        const float zaB = __builtin_amdgcn_rcpf(1.0f + __expf(-dB[st][qt][2 * h2]));
                        const float zbB = __builtin_amdgcn_rcpf(1.0f + __expf(-dB[st][qt][2 * h2 + 1]));
                        pkB[st][qt][h2] = (unsigned int)f2bf(zaB) |
                                          ((unsigned int)f2bf(zbB) << 16);
                    }

            // redistribute D^T -> P A-frag: lane (lk,lr) needs P[s=lk*8+i][q=qt*16+lr]
            const int srcA = ((lk & 1) * 2) * 16 + lr;
            short8 paA[2], paB[2];
            #pragma unroll
            for (int qt = 0; qt < 2; ++qt) {
                union { unsigned int u[4]; short8 s; } ua, ub;
                #pragma unroll
                for (int jp = 0; jp < 4; ++jp) {
                    const int src = srcA + (jp >> 1) * 16;
                    const int vA0 = __shfl((int)pkA[0][qt][jp & 1], src, 64);
                    const int vA1 = __shfl((int)pkA[1][qt][jp & 1], src, 64);
                    ua.u[jp] = (lk < 2) ? (unsigned int)vA0 : (unsigned int)vA1;
                    const int vB0 = __shfl((int)pkB[0][qt][jp & 1], src, 64);
                    const int vB1 = __shfl((int)pkB[1][qt][jp & 1], src, 64);
                    ub.u[jp] = (lk < 2) ? (unsigned int)vB0 : (unsigned int)vB1;
                }
                paA[qt] = ua.s;
                paB[qt] = ub.s;
            }

            // PV: B-frag from V^T; o[q][dv]
            const int kkg = g & 3;
            short8 vbA[2], vbB[2];
            #pragma unroll
            for (int dvt = 0; dvt < 2; ++dvt) {
                const int dv = dvt * 16 + lr;
                const int off = kkg * 1024 + dv * 32 + ((lk * 8) ^ ((dv & 3) << 3));
                vbA[dvt] = *(const short8*)&vbufA[off];
                vbB[dvt] = *(const short8*)&vbufB[off];
            }
            f32x4 oA[2][2] = {}, oB[2][2] = {};
            #pragma unroll
            for (int qt = 0; qt < 2; ++qt)
                #pragma unroll
                for (int dvt = 0; dvt < 2; ++dvt) {
                    oA[qt][dvt] = MFMA(paA[qt], vbA[dvt], oA[qt][dvt]);
                    oB[qt][dvt] = MFMA(paB[qt], vbB[dvt], oB[qt][dvt]);
                }

            // write o -> obufA/B bf16 (swizzled)
            #pragma unroll
            for (int qt = 0; qt < 2; ++qt)
                #pragma unroll
                for (int dvt = 0; dvt < 2; ++dvt)
                    #pragma unroll
                    for (int r = 0; r < 4; ++r) {
                        const int q = qt * 16 + lk * 4 + r;
                        const int col = g * 32 + dvt * 16 + lr;
                        const int off = q * 256 + (col ^ ((q & 7) << 3));
                        obufA[off] = (short)f2bf(oA[qt][dvt][r]);
                        obufB[off] = (short)f2bf(oB[qt][dvt][r]);
                    }
        }
        __syncthreads();   // barrier 2: o (both slices) visible

        // ---------- out projection: oacc += oA x WoA + oB x WoB ----------
        // (no barrier after: next pair's obuf writes are fenced transitively
        //  by the next pair's barrier 1; q/k/v rewrites don't touch obuf)
        {
            #pragma unroll 2
            for (int ks = 0; ks < 8; ++ks) {
                const int e = (ks * 32 + lk * 8) ^ aswz;
                const short8 aA0 = *(const short8*)&obufA[lr * 256 + e];
                const short8 aA1 = *(const short8*)&obufA[(16 + lr) * 256 + e];
                const short8 aB0 = *(const short8*)&obufB[lr * 256 + e];
                const short8 aB1 = *(const short8*)&obufB[(16 + lr) * 256 + e];
                const short8 bA0 = wsOv[(size_t)((advA * 8 + ks) * 16 + w * 2 + 0) * 64 + l];
                const short8 bA1 = wsOv[(size_t)((advA * 8 + ks) * 16 + w * 2 + 1) * 64 + l];
                const short8 bB0 = wsOv[(size_t)((advB * 8 + ks) * 16 + w * 2 + 0) * 64 + l];
                const short8 bB1 = wsOv[(size_t)((advB * 8 + ks) * 16 + w * 2 + 1) * 64 + l];
                oacc[0][0] = MFMA(aA0, bA0, oacc[0][0]);
                oacc[1][0] = MFMA(aA1, bA0, oacc[1][0]);
                oacc[0][1] = MFMA(aA0, bA1, oacc[0][1]);
                oacc[1][1] = MFMA(aA1, bA1, oacc[1][1]);
                oacc[0][0] = MFMA(aB0, bB0, oacc[0][0]);
                oacc[1][0] = MFMA(aB1, bB0, oacc[1][0]);
                oacc[0][1] = MFMA(aB0, bB1, oacc[0][1]);
                oacc[1][1] = MFMA(aB1, bB1, oacc[1][1]);
            }
        }
    }

    // ---------- write / accumulate output ----------
    #pragma unroll
    for (int mt = 0; mt < 2; ++mt)
        #pragma unroll
        for (int nt = 0; nt < 2; ++nt)
            #pragma unroll
            for (int r = 0; r < 4; ++r) {
                const int pos = mt * 16 + lk * 4 + r;
                const int c = w * 32 + nt * 16 + lr;
                const int gy = (AXIS == 0) ? pos : line;
                const int gx = (AXIS == 0) ? line : pos;
                float* po = out + ((size_t)((b * 32 + gy) * 32 + gx)) * 256 + c;
                if (ACCUM) *po += oacc[mt][nt][r];
                else       *po = oacc[mt][nt][r];
            }
}

} // namespace

extern "C" void kernel_launch(void* const* d_in, const int* in_sizes, int n_in,
                              void* d_out, int out_size, void* d_ws, size_t ws_size,
                              hipStream_t stream) {
    (void)in_sizes; (void)n_in; (void)out_size; (void)ws_size;
    const float* x     = (const float*)d_in[0];
    const float* xpos  = (const float*)d_in[1];
    const float* ypos  = (const float*)d_in[2];
    const float* Wq    = (const float*)d_in[3];
    const float* Wk    = (const float*)d_in[4];
    const float* Wv    = (const float*)d_in[5];
    const float* bv    = (const float*)d_in[6];
    const float* Wo    = (const float*)d_in[7];
    const float* rfreq = (const float*)d_in[8];
    float* out = (float*)d_out;

    short* wsQ  = (short*)d_ws;                 // 1 MB
    short* wsKV = wsQ + 1024 * 512;             // 1 MB
    short* wsO  = wsKV + 1024 * 512;            // 1 MB

    prep_weights<<<dim3(768), dim3(256), 0, stream>>>(Wq, Wk, Wv, Wo, wsQ, wsKV, wsO);
    axial_attn_mfma<0, false><<<dim3(1024), dim3(512), 0, stream>>>(
        x, xpos, ypos, bv, rfreq, wsQ, wsKV, wsO, out);
    axial_attn_mfma<1, true><<<dim3(1024), dim3(512), 0, stream>>>(
        x, xpos, ypos, bv, rfreq, wsQ, wsKV, wsO, out);
}